// Round 12
// baseline (216.622 us; speedup 1.0000x reference)
//
#include <hip/hip_runtime.h>
#include <math.h>

// Problem constants (match reference setup_inputs)
#define SB 196   // spatial s = h*w = 14*14
#define SP 224   // s padded to 7*32 for MFMA K-steps
#define NB 8     // batch
#define NC 2048  // channels
#define ND 1024  // INTER_DIM
#define NN 80    // NUM_CLASSES
#define NW 300   // WORD_DIM
#define CH 16    // d-chunks in k2a
#define DCH (ND / CH)   // 64

typedef __bf16 v8bf __attribute__((ext_vector_type(8)));
typedef __bf16 v4bf __attribute__((ext_vector_type(4)));
typedef float  f32x4 __attribute__((ext_vector_type(4)));

// ---------------------------------------------------------------------------
// K0a: v[d] = sum_e Wa[e] * W3[e][d]   (Wa @ W3), accumulated via atomics.
// ---------------------------------------------------------------------------
__global__ __launch_bounds__(256) void k0_v(const float* __restrict__ W3,
                                            const float* __restrict__ Wa,
                                            float* __restrict__ v) {
    int d  = blockIdx.x * 256 + threadIdx.x;
    int e0 = blockIdx.y * 64;
    float p = 0.f;
    #pragma unroll 8
    for (int e = e0; e < e0 + 64; ++e) {
        p += Wa[e] * W3[(size_t)e * ND + d];   // coalesced over d
    }
    atomicAdd(&v[d], p);
}

// ---------------------------------------------------------------------------
// K0b: fwd[n][d] = sum_w word[n][w] * W2[d][w]; emits
//   wpack[n][d] = { 2*log2(e)*fwd, -2*v[d] }
// k2a computes logit' = sum_d wy / (1 + 2^(F*wx)) = ref logit - sum(v)
// (s-uniform constant, cancels in softmax over s). Runs after k0_v.
// ---------------------------------------------------------------------------
__global__ __launch_bounds__(256) void k0_fwd(const float* __restrict__ word,
                                              const float* __restrict__ W2,
                                              const float* __restrict__ v,
                                              float2* __restrict__ wpack) {
    __shared__ __align__(16) float lword[NW];
    int n = blockIdx.x;
    int d = blockIdx.y * 256 + threadIdx.x;
    for (int i = threadIdx.x; i < NW; i += 256) lword[i] = word[(size_t)n * NW + i];
    __syncthreads();
    const float4* wr = (const float4*)(W2 + (size_t)d * NW);
    const float4* l4 = (const float4*)lword;
    float acc = 0.f;
    #pragma unroll 5
    for (int i = 0; i < NW / 4; ++i) {
        float4 a = wr[i], b = l4[i];
        acc += a.x * b.x + a.y * b.y + a.z * b.z + a.w * b.w;
    }
    float2 o;
    o.x = 2.8853900817779268f * acc;   // 2*log2(e) * fwd[n][d]
    o.y = -2.f * v[d];
    wpack[(size_t)n * ND + d] = o;
}

// ---------------------------------------------------------------------------
// kcast_x: ONE pass over X [b][c][s] fp32 producing
//   Xt  [b][s][c]  bf16 (transposed, for k1 fragments)
//   Xhi/Xlo [b][c][224] bf16 split (for k3), zero s-pad
// grid (32 c-tiles, 4 s-tiles, 9): z<8 = batch slice; z==8 = W1 fp32->bf16.
// ---------------------------------------------------------------------------
__global__ __launch_bounds__(256) void kcast_x(const float* __restrict__ X,
                                               const float* __restrict__ W1,
                                               __bf16* __restrict__ Xt,
                                               __bf16* __restrict__ Xhi,
                                               __bf16* __restrict__ Xlo,
                                               __bf16* __restrict__ W1b) {
    const int t = threadIdx.x;
    if (blockIdx.z == 8) {
        unsigned int slice_tid = (blockIdx.x * 4 + blockIdx.y) * 256 + t;
        #pragma unroll 4
        for (int r = 0; r < 16; ++r) {
            size_t i = ((size_t)slice_tid + (size_t)r * 32768) * 4;
            float4 f = *(const float4*)(W1 + i);
            v4bf o;
            o[0] = (__bf16)f.x; o[1] = (__bf16)f.y;
            o[2] = (__bf16)f.z; o[3] = (__bf16)f.w;
            *(v4bf*)(W1b + i) = o;
        }
        return;
    }
    __shared__ float tile[64][65];   // [c][s], +1 pad
    const int b  = blockIdx.z;
    const int c0 = blockIdx.x * 64;
    const int s0 = blockIdx.y * 64;
    const float* Xb = X + (size_t)b * NC * SB;
    {   // read: coalesced over s
        int ss = t & 63, cbase = t >> 6;
        #pragma unroll
        for (int r = 0; r < 16; ++r) {
            int cc = cbase + 4 * r;
            float val = (s0 + ss < SB) ? Xb[(size_t)(c0 + cc) * SB + s0 + ss] : 0.f;
            tile[cc][ss] = val;
        }
    }
    __syncthreads();
    {   // write 1: Xt transposed, coalesced over c
        int cc = t & 63, sbase = t >> 6;
        #pragma unroll
        for (int r = 0; r < 16; ++r) {
            int ss = sbase + 4 * r;
            if (s0 + ss < SB)
                Xt[((size_t)b * SB + s0 + ss) * NC + c0 + cc] = (__bf16)tile[cc][ss];
        }
    }
    {   // write 2: Xhi/Xlo direct orientation; zero the pad
        int ss = t & 63, cbase = t >> 6;
        int sg = s0 + ss;
        #pragma unroll
        for (int r = 0; r < 16; ++r) {
            int cc = cbase + 4 * r;
            if (sg < SP) {
                float val = (sg < SB) ? tile[cc][ss] : 0.f;
                __bf16 h = (__bf16)val;
                __bf16 l = (__bf16)(val - (float)h);
                size_t base = ((size_t)b * NC + c0 + cc) * SP + sg;
                Xhi[base] = h;
                Xlo[base] = l;
            }
        }
    }
}

// ---------------------------------------------------------------------------
// K1 v2 (direct-fragment MFMA, no LDS, no barriers):
// F[b][d][s] = sum_c W1[d][c] * X[b][c][s], bf16 in, fp32 out.
// The old LDS round-trip was a pure copy: each lane's fragment is exactly
// W1b[(d0+doff+l16)*NC + k0 + quad*8] (resp. Xt row for B). A wave's 64
// lanes touch 16 rows x 64 contiguous B per fragment pair (full line use);
// W1b is L2-resident; the 2-wave/block row duplication hits L1 (4KB/K-step).
// #pragma unroll 4 lets the compiler interleave 16 outstanding loads with
// 16 MFMAs (AITER-style) -- no s_barrier drain anywhere.
// grid (16 d-tiles, 4 s-tiles, 8 b), block 256 (4 waves, 32x32 quadrants).
// ---------------------------------------------------------------------------
__global__ __launch_bounds__(256) void k1_mfma(const __bf16* __restrict__ Xt,
                                               const __bf16* __restrict__ W1b,
                                               float* __restrict__ F) {
    const int t    = threadIdx.x;
    const int d0   = blockIdx.x * 64;
    const int s0   = blockIdx.y * 64;
    const int b    = blockIdx.z;
    const int lane = t & 63;
    const int wave = t >> 6;
    const int doff = (wave & 1) * 32;
    const int soff = (wave >> 1) * 32;
    const int quad = lane >> 4;
    const int l16  = lane & 15;

    f32x4 acc[2][2] = {};

    const int rowA = d0 + doff + l16;
    const int rowB0 = s0 + soff + l16;
    const int rowB1 = rowB0 + 16;
    const bool sv0 = rowB0 < SB;
    const bool sv1 = rowB1 < SB;
    const __bf16* A0p = W1b + (size_t)rowA * NC + quad * 8;
    const __bf16* A1p = A0p + (size_t)16 * NC;
    const __bf16* B0p = Xt + ((size_t)b * SB + (sv0 ? rowB0 : 0)) * NC + quad * 8;
    const __bf16* B1p = Xt + ((size_t)b * SB + (sv1 ? rowB1 : 0)) * NC + quad * 8;
    const uint4 z = make_uint4(0u, 0u, 0u, 0u);

    #pragma unroll 4
    for (int k0 = 0; k0 < NC; k0 += 32) {
        uint4 ua0 = *(const uint4*)(A0p + k0);
        uint4 ua1 = *(const uint4*)(A1p + k0);
        uint4 ub0 = sv0 ? *(const uint4*)(B0p + k0) : z;
        uint4 ub1 = sv1 ? *(const uint4*)(B1p + k0) : z;
        v8bf a0 = *(const v8bf*)&ua0;
        v8bf a1 = *(const v8bf*)&ua1;
        v8bf b0 = *(const v8bf*)&ub0;
        v8bf b1 = *(const v8bf*)&ub1;
        acc[0][0] = __builtin_amdgcn_mfma_f32_16x16x32_bf16(a0, b0, acc[0][0], 0, 0, 0);
        acc[0][1] = __builtin_amdgcn_mfma_f32_16x16x32_bf16(a0, b1, acc[0][1], 0, 0, 0);
        acc[1][0] = __builtin_amdgcn_mfma_f32_16x16x32_bf16(a1, b0, acc[1][0], 0, 0, 0);
        acc[1][1] = __builtin_amdgcn_mfma_f32_16x16x32_bf16(a1, b1, acc[1][1], 0, 0, 0);
    }
    // epilogue: D[row = quad*4+r (d), col = l16 (s)] -- unchanged convention
    float* Fb = F + (size_t)b * ND * SB;
    #pragma unroll
    for (int i = 0; i < 2; ++i) {
        #pragma unroll
        for (int j = 0; j < 2; ++j) {
            int s = s0 + soff + j * 16 + l16;
            if (s < SB) {
                #pragma unroll
                for (int r = 0; r < 4; ++r) {
                    int d = d0 + doff + i * 16 + quad * 4 + r;
                    Fb[(size_t)d * SB + s] = acc[i][j][r];
                }
            }
        }
    }
}

// ---------------------------------------------------------------------------
// K2a v4: partial logits, 8-way n-tiling x 16 d-chunks (unchanged from R11).
// part[ch][b][n][s] = sum_{d in chunk} wy/(1 + 2^(F*wx))
// grid (10 n-groups, 7 bs-tiles, 16 ch) = 1120 blocks, block 256.
// ---------------------------------------------------------------------------
__global__ __launch_bounds__(256) void k2a(const float* __restrict__ F,
                                           const float2* __restrict__ wpack,
                                           float* __restrict__ part) {
    const int n0  = blockIdx.x * 8;
    const int ch  = blockIdx.z;
    const int idx = blockIdx.y * 256 + threadIdx.x;   // (b,s) flat, valid <1568
    const bool valid = idx < (NB * SB);
    const int iv = valid ? idx : 0;
    const int b  = iv / SB;          // magic-mul div by 196
    const int s  = iv - b * SB;
    const float*  Fp    = F + ((size_t)b * ND + ch * DCH) * SB + s;
    const float2* wbase = wpack + ch * DCH;
    float a[8] = {};
    #pragma unroll 2
    for (int d2 = 0; d2 < DCH / 2; ++d2) {
        float f0 = Fp[(size_t)(2 * d2)     * SB];
        float f1 = Fp[(size_t)(2 * d2 + 1) * SB];
        #pragma unroll
        for (int j = 0; j < 8; ++j) {
            float4 w = *(const float4*)(wbase + (size_t)(n0 + j) * ND + 2 * d2);
            float e0 = __builtin_amdgcn_exp2f(f0 * w.x);
            float e1 = __builtin_amdgcn_exp2f(f1 * w.z);
            a[j] = fmaf(w.y, __builtin_amdgcn_rcpf(1.f + e0), a[j]);
            a[j] = fmaf(w.w, __builtin_amdgcn_rcpf(1.f + e1), a[j]);
        }
    }
    if (valid) {
        size_t base = ((size_t)ch * NB + b) * NN;
        #pragma unroll
        for (int j = 0; j < 8; ++j)
            part[(base + n0 + j) * 256 + s] = a[j];
    }
}

// ---------------------------------------------------------------------------
// K2b: sum 16 chunks, softmax over s, write split bf16 coef (SP-padded).
// grid (80 n, 8 b), block 256.
// ---------------------------------------------------------------------------
__global__ __launch_bounds__(256) void k2b(const float* __restrict__ part,
                                           __bf16* __restrict__ coefh,
                                           __bf16* __restrict__ coefl) {
    __shared__ float red[256];
    const int n = blockIdx.x;
    const int b = blockIdx.y;
    const int t = threadIdx.x;
    float acc = 0.f;
    #pragma unroll
    for (int ch = 0; ch < CH; ++ch)
        acc += part[(((size_t)ch * NB + b) * NN + n) * 256 + t];

    red[t] = (t < SB) ? acc : -1e30f;
    __syncthreads();
    #pragma unroll
    for (int off = 128; off > 0; off >>= 1) {
        if (t < off) red[t] = fmaxf(red[t], red[t + off]);
        __syncthreads();
    }
    float m = red[0];
    __syncthreads();
    float p = (t < SB) ? __expf(acc - m) : 0.f;
    red[t] = p;
    __syncthreads();
    #pragma unroll
    for (int off = 128; off > 0; off >>= 1) {
        if (t < off) red[t] += red[t + off];
        __syncthreads();
    }
    float inv = 1.f / red[0];
    if (t < SP) {
        float val = (t < SB) ? p * inv : 0.f;
        __bf16 h = (__bf16)val;
        __bf16 l = (__bf16)(val - (float)h);
        size_t base = ((size_t)b * NN + n) * SP + t;
        coefh[base] = h;
        coefl[base] = l;
    }
}

// ---------------------------------------------------------------------------
// K3 (MFMA, split precision): out[b][n][c] = sum_s coef[b][n][s] * X[b][c][s]
// out ~= Ah*Bh + Al*Bh + Ah*Bl. grid (32 c-tiles, 8 b), block 256.
// ---------------------------------------------------------------------------
__global__ __launch_bounds__(256) void k3_mfma(const __bf16* __restrict__ Xhi,
                                               const __bf16* __restrict__ Xlo,
                                               const __bf16* __restrict__ coefh,
                                               const __bf16* __restrict__ coefl,
                                               float* __restrict__ out) {
    const int t     = threadIdx.x;
    const int wave  = t >> 6;
    const int lane  = t & 63;
    const int quad  = lane >> 4;
    const int l16   = lane & 15;
    const int b     = blockIdx.y;
    const int cbase = blockIdx.x * 64 + wave * 16;

    const __bf16* Bh = Xhi + ((size_t)b * NC + cbase + l16) * SP + quad * 8;
    const __bf16* Bl = Xlo + ((size_t)b * NC + cbase + l16) * SP + quad * 8;
    const __bf16* Ah = coefh + ((size_t)b * NN + l16) * SP + quad * 8;
    const __bf16* Al = coefl + ((size_t)b * NN + l16) * SP + quad * 8;

    f32x4 acc[5] = {};

    #pragma unroll
    for (int k0 = 0; k0 < SP; k0 += 32) {
        v8bf bh = *(const v8bf*)(Bh + k0);
        v8bf bl = *(const v8bf*)(Bl + k0);
        #pragma unroll
        for (int mt = 0; mt < 5; ++mt) {
            v8bf ah = *(const v8bf*)(Ah + (size_t)mt * 16 * SP + k0);
            v8bf al = *(const v8bf*)(Al + (size_t)mt * 16 * SP + k0);
            acc[mt] = __builtin_amdgcn_mfma_f32_16x16x32_bf16(ah, bh, acc[mt], 0, 0, 0);
            acc[mt] = __builtin_amdgcn_mfma_f32_16x16x32_bf16(al, bh, acc[mt], 0, 0, 0);
            acc[mt] = __builtin_amdgcn_mfma_f32_16x16x32_bf16(ah, bl, acc[mt], 0, 0, 0);
        }
    }
    #pragma unroll
    for (int mt = 0; mt < 5; ++mt) {
        #pragma unroll
        for (int r = 0; r < 4; ++r) {
            int n = mt * 16 + quad * 4 + r;
            out[((size_t)b * NN + n) * NC + cbase + l16] = acc[mt][r];
        }
    }
}

// ---------------------------------------------------------------------------
// Workspace layout — NO aliasing (ws ~256 MB; peak use ~43 MB):
//   v(4K) | wpack(640K) | part(10.5M) | coefh(280K) | coefl(280K) |
//   W1b(4M) | Xt(6.42M) | F(6.42M) | Xhi(7.34M) | Xlo(7.34M)
// ---------------------------------------------------------------------------
extern "C" void kernel_launch(void* const* d_in, const int* in_sizes, int n_in,
                              void* d_out, int out_size, void* d_ws, size_t ws_size,
                              hipStream_t stream) {
    const float* X    = (const float*)d_in[0];  // [8][2048][196]
    const float* word = (const float*)d_in[1];  // [80][300]
    const float* W1   = (const float*)d_in[2];  // [1024][2048]
    const float* W2   = (const float*)d_in[3];  // [1024][300]
    const float* W3   = (const float*)d_in[4];  // [1024][1024]
    // d_in[5] = b3, d_in[7] = ba: cancel in softmax (uniform over s) -> unused
    const float* Wa   = (const float*)d_in[6];  // [1][1024]
    float* out = (float*)d_out;

    char* ws = (char*)d_ws;
    float*  v     = (float*)ws;                             // 1024 f
    float2* wpack = (float2*)(v + ND);                      // 80*1024 float2
    float*  part  = (float*)(wpack + (size_t)NN * ND);      // 16*8*80*256 f
    __bf16* coefh = (__bf16*)(part + (size_t)CH * NB * NN * 256);
    __bf16* coefl = coefh + (size_t)NB * NN * SP;
    __bf16* W1b   = coefl + (size_t)NB * NN * SP;           // 4.00 MB
    __bf16* Xt    = W1b + (size_t)ND * NC;                  // 6.42 MB
    float*  F     = (float*)(Xt + (size_t)NB * SB * NC);    // 6.42 MB
    __bf16* Xhi   = (__bf16*)(F + (size_t)NB * ND * SB);    // 7.34 MB
    __bf16* Xlo   = Xhi + (size_t)NB * NC * SP;             // 7.34 MB

    hipMemsetAsync(v, 0, ND * sizeof(float), stream);
    k0_v   <<<dim3(4, 16),        256, 0, stream>>>(W3, Wa, v);
    k0_fwd <<<dim3(NN, 4),        256, 0, stream>>>(word, W2, v, wpack);
    kcast_x<<<dim3(32, 4, 9),     256, 0, stream>>>(X, W1, Xt, Xhi, Xlo, W1b);
    k1_mfma<<<dim3(16, 4, NB),    256, 0, stream>>>(Xt, W1b, F);
    k2a    <<<dim3(10, 7, CH),    256, 0, stream>>>(F, wpack, part);
    k2b    <<<dim3(NN, NB),       256, 0, stream>>>(part, coefh, coefl);
    k3_mfma<<<dim3(NC / 64, NB),  256, 0, stream>>>(Xhi, Xlo, coefh, coefl, out);
}

// Round 13
// 209.623 us; speedup vs baseline: 1.0334x; 1.0334x over previous
//
#include <hip/hip_runtime.h>
#include <math.h>

// Problem constants (match reference setup_inputs)
#define SB 196   // spatial s = h*w = 14*14
#define SP 224   // s padded to 7*32 for MFMA K-steps
#define NB 8     // batch
#define NC 2048  // channels
#define ND 1024  // INTER_DIM
#define NN 80    // NUM_CLASSES
#define NW 300   // WORD_DIM
#define CH 8     // d-chunks in k2a
#define DCH (ND / CH)   // 128
#define KS 4     // K-split in k1 (NC/KS = 512 per block)

typedef __bf16 v8bf __attribute__((ext_vector_type(8)));
typedef __bf16 v4bf __attribute__((ext_vector_type(4)));
typedef float  f32x4 __attribute__((ext_vector_type(4)));

// ---------------------------------------------------------------------------
// K0a: v[d] = sum_e Wa[e] * W3[e][d]   (Wa @ W3), accumulated via atomics.
// ---------------------------------------------------------------------------
__global__ __launch_bounds__(256) void k0_v(const float* __restrict__ W3,
                                            const float* __restrict__ Wa,
                                            float* __restrict__ v) {
    int d  = blockIdx.x * 256 + threadIdx.x;
    int e0 = blockIdx.y * 64;
    float p = 0.f;
    #pragma unroll 8
    for (int e = e0; e < e0 + 64; ++e) {
        p += Wa[e] * W3[(size_t)e * ND + d];   // coalesced over d
    }
    atomicAdd(&v[d], p);
}

// ---------------------------------------------------------------------------
// K0b: fwd[n][d] = sum_w word[n][w] * W2[d][w]; emits
//   wpack[n][d] = { 2*log2(e)*fwd, -2*v[d] }
// k2a computes logit' = sum_d wy / (1 + 2^(F*wx)) = ref logit - sum(v)
// (s-uniform constant, cancels in softmax over s). Runs after k0_v.
// ---------------------------------------------------------------------------
__global__ __launch_bounds__(256) void k0_fwd(const float* __restrict__ word,
                                              const float* __restrict__ W2,
                                              const float* __restrict__ v,
                                              float2* __restrict__ wpack) {
    __shared__ __align__(16) float lword[NW];
    int n = blockIdx.x;
    int d = blockIdx.y * 256 + threadIdx.x;
    for (int i = threadIdx.x; i < NW; i += 256) lword[i] = word[(size_t)n * NW + i];
    __syncthreads();
    const float4* wr = (const float4*)(W2 + (size_t)d * NW);
    const float4* l4 = (const float4*)lword;
    float acc = 0.f;
    #pragma unroll 5
    for (int i = 0; i < NW / 4; ++i) {
        float4 a = wr[i], b = l4[i];
        acc += a.x * b.x + a.y * b.y + a.z * b.z + a.w * b.w;
    }
    float2 o;
    o.x = 2.8853900817779268f * acc;   // 2*log2(e) * fwd[n][d]
    o.y = -2.f * v[d];
    wpack[(size_t)n * ND + d] = o;
}

// ---------------------------------------------------------------------------
// kcast_x: ONE pass over X [b][c][s] fp32 producing
//   Xt  [b][s][c]  bf16 (transposed, for k1 staging)
//   Xhi/Xlo [b][c][224] bf16 split (for k3), zero s-pad
// grid (32 c-tiles, 4 s-tiles, 9): z<8 = batch slice; z==8 = W1 fp32->bf16
// cast + F zero-init (k1 accumulates into F with atomics; stream order
// guarantees this completes before k1 starts).
// ---------------------------------------------------------------------------
__global__ __launch_bounds__(256) void kcast_x(const float* __restrict__ X,
                                               const float* __restrict__ W1,
                                               __bf16* __restrict__ Xt,
                                               __bf16* __restrict__ Xhi,
                                               __bf16* __restrict__ Xlo,
                                               __bf16* __restrict__ W1b,
                                               float* __restrict__ F) {
    const int t = threadIdx.x;
    if (blockIdx.z == 8) {
        unsigned int slice_tid = (blockIdx.x * 4 + blockIdx.y) * 256 + t;
        #pragma unroll 4
        for (int r = 0; r < 16; ++r) {
            size_t i = ((size_t)slice_tid + (size_t)r * 32768) * 4;
            float4 f = *(const float4*)(W1 + i);
            v4bf o;
            o[0] = (__bf16)f.x; o[1] = (__bf16)f.y;
            o[2] = (__bf16)f.z; o[3] = (__bf16)f.w;
            *(v4bf*)(W1b + i) = o;
        }
        // zero F: 8*1024*196 = 1,605,632 floats = 401,408 float4
        const float4 z4 = make_float4(0.f, 0.f, 0.f, 0.f);
        #pragma unroll
        for (int r = 0; r < 13; ++r) {
            unsigned int idx = slice_tid + r * 32768u;
            if (idx < 401408u) ((float4*)F)[idx] = z4;
        }
        return;
    }
    __shared__ float tile[64][65];   // [c][s], +1 pad
    const int b  = blockIdx.z;
    const int c0 = blockIdx.x * 64;
    const int s0 = blockIdx.y * 64;
    const float* Xb = X + (size_t)b * NC * SB;
    {   // read: coalesced over s
        int ss = t & 63, cbase = t >> 6;
        #pragma unroll
        for (int r = 0; r < 16; ++r) {
            int cc = cbase + 4 * r;
            float val = (s0 + ss < SB) ? Xb[(size_t)(c0 + cc) * SB + s0 + ss] : 0.f;
            tile[cc][ss] = val;
        }
    }
    __syncthreads();
    {   // write 1: Xt transposed, coalesced over c
        int cc = t & 63, sbase = t >> 6;
        #pragma unroll
        for (int r = 0; r < 16; ++r) {
            int ss = sbase + 4 * r;
            if (s0 + ss < SB)
                Xt[((size_t)b * SB + s0 + ss) * NC + c0 + cc] = (__bf16)tile[cc][ss];
        }
    }
    {   // write 2: Xhi/Xlo direct orientation; zero the pad
        int ss = t & 63, cbase = t >> 6;
        int sg = s0 + ss;
        #pragma unroll
        for (int r = 0; r < 16; ++r) {
            int cc = cbase + 4 * r;
            if (sg < SP) {
                float val = (sg < SB) ? tile[cc][ss] : 0.f;
                __bf16 h = (__bf16)val;
                __bf16 l = (__bf16)(val - (float)h);
                size_t base = ((size_t)b * NC + c0 + cc) * SP + sg;
                Xhi[base] = h;
                Xlo[base] = l;
            }
        }
    }
}

// ---------------------------------------------------------------------------
// K1 (MFMA, K-split x4): F[b][d][s] += sum_{c in split} W1[d][c] * X[b][c][s]
// EXACT R3-proven LDS staging / K-loop / fragment layout; only changes:
// (1) each block covers 512 of NC (16 K-steps), (2) epilogue uses atomicAdd
// (F zero-initialized by kcast_x). 2048 blocks = 8 blocks/CU = 32 waves/CU
// (LDS 8 x 16.5KB = 132KB < 160KB) -- fixes the 2-waves/SIMD latency
// serialization measured in R12 post-mortem (97% stall at 2 blocks/CU).
// grid (16 d-tiles, 4 s-tiles, 8b*4ks), block 256.
// ---------------------------------------------------------------------------
#define PITCH 40
__global__ __launch_bounds__(256) void k1_mfma(const __bf16* __restrict__ Xt,
                                               const __bf16* __restrict__ W1b,
                                               float* __restrict__ F) {
    __shared__ __align__(16) __bf16 lA[64 * PITCH];
    __shared__ __align__(16) __bf16 lB[64 * PITCH];
    const int t    = threadIdx.x;
    const int d0   = blockIdx.x * 64;
    const int s0   = blockIdx.y * 64;
    const int b    = blockIdx.z & 7;
    const int ks   = blockIdx.z >> 3;         // 0..3
    const int kbase = ks * (NC / KS);         // 0,512,1024,1536
    const int lane = t & 63;
    const int wave = t >> 6;
    const int doff = (wave & 1) * 32;
    const int soff = (wave >> 1) * 32;
    const int quad = lane >> 4;
    const int l16  = lane & 15;

    f32x4 acc[2][2] = {};

    const int rr = t >> 2;
    const int cc = (t & 3) * 8;
    const bool sv = (s0 + rr) < SB;
    const __bf16* Ag = W1b + (size_t)(d0 + rr) * NC + cc;
    const __bf16* Bg = Xt + ((size_t)b * SB + (sv ? (s0 + rr) : 0)) * NC + cc;
    __bf16* lAw = lA + rr * PITCH + cc;
    __bf16* lBw = lB + rr * PITCH + cc;

    const __bf16* rA0 = lA + (doff + l16) * PITCH + quad * 8;
    const __bf16* rA1 = rA0 + 16 * PITCH;
    const __bf16* rB0 = lB + (soff + l16) * PITCH + quad * 8;
    const __bf16* rB1 = rB0 + 16 * PITCH;

    for (int k0 = kbase; k0 < kbase + NC / KS; k0 += 32) {
        uint4 a = *(const uint4*)(Ag + k0);
        uint4 bv = sv ? *(const uint4*)(Bg + k0) : make_uint4(0u, 0u, 0u, 0u);
        __syncthreads();
        *(uint4*)lAw = a;
        *(uint4*)lBw = bv;
        __syncthreads();
        v8bf a0 = *(const v8bf*)rA0;
        v8bf a1 = *(const v8bf*)rA1;
        v8bf b0 = *(const v8bf*)rB0;
        v8bf b1 = *(const v8bf*)rB1;
        acc[0][0] = __builtin_amdgcn_mfma_f32_16x16x32_bf16(a0, b0, acc[0][0], 0, 0, 0);
        acc[0][1] = __builtin_amdgcn_mfma_f32_16x16x32_bf16(a0, b1, acc[0][1], 0, 0, 0);
        acc[1][0] = __builtin_amdgcn_mfma_f32_16x16x32_bf16(a1, b0, acc[1][0], 0, 0, 0);
        acc[1][1] = __builtin_amdgcn_mfma_f32_16x16x32_bf16(a1, b1, acc[1][1], 0, 0, 0);
    }
    // epilogue: atomic accumulate (4 K-split writers per element)
    float* Fb = F + (size_t)b * ND * SB;
    #pragma unroll
    for (int i = 0; i < 2; ++i) {
        #pragma unroll
        for (int j = 0; j < 2; ++j) {
            int s = s0 + soff + j * 16 + l16;
            if (s < SB) {
                #pragma unroll
                for (int r = 0; r < 4; ++r) {
                    int d = d0 + doff + i * 16 + quad * 4 + r;
                    atomicAdd(&Fb[(size_t)d * SB + s], acc[i][j][r]);
                }
            }
        }
    }
}

// ---------------------------------------------------------------------------
// K2a v3 (R9-measured-best): partial logits, 4-way n-tiling x 8 d-chunks.
// part[ch][b][n][s] = sum_{d in chunk} wy/(1 + 2^(F*wx))
// grid (20 n-groups, 7 bs-tiles, 8 ch), block 256: idx = by*256+t over (b,s).
// ---------------------------------------------------------------------------
__global__ __launch_bounds__(256) void k2a(const float* __restrict__ F,
                                           const float2* __restrict__ wpack,
                                           float* __restrict__ part) {
    const int n0  = blockIdx.x * 4;
    const int ch  = blockIdx.z;
    const int idx = blockIdx.y * 256 + threadIdx.x;   // (b,s) flat, valid <1568
    const bool valid = idx < (NB * SB);
    const int iv = valid ? idx : 0;
    const int b  = iv / SB;          // magic-mul div by 196
    const int s  = iv - b * SB;
    const float*  Fp  = F + ((size_t)b * ND + ch * DCH) * SB + s;
    const float4* wp0 = (const float4*)(wpack + (size_t)(n0 + 0) * ND + ch * DCH);
    const float4* wp1 = (const float4*)(wpack + (size_t)(n0 + 1) * ND + ch * DCH);
    const float4* wp2 = (const float4*)(wpack + (size_t)(n0 + 2) * ND + ch * DCH);
    const float4* wp3 = (const float4*)(wpack + (size_t)(n0 + 3) * ND + ch * DCH);
    float a0 = 0.f, a1 = 0.f, a2 = 0.f, a3 = 0.f;
    #pragma unroll 4
    for (int d2 = 0; d2 < DCH / 2; ++d2) {
        float f0 = Fp[(size_t)(2 * d2)     * SB];
        float f1 = Fp[(size_t)(2 * d2 + 1) * SB];
        float4 w0 = wp0[d2];   // {wx0, wy0, wx1, wy1} wave-uniform s_load
        float4 w1 = wp1[d2];
        float4 w2 = wp2[d2];
        float4 w3 = wp3[d2];
        float e00 = __builtin_amdgcn_exp2f(f0 * w0.x);
        float e01 = __builtin_amdgcn_exp2f(f1 * w0.z);
        float e10 = __builtin_amdgcn_exp2f(f0 * w1.x);
        float e11 = __builtin_amdgcn_exp2f(f1 * w1.z);
        float e20 = __builtin_amdgcn_exp2f(f0 * w2.x);
        float e21 = __builtin_amdgcn_exp2f(f1 * w2.z);
        float e30 = __builtin_amdgcn_exp2f(f0 * w3.x);
        float e31 = __builtin_amdgcn_exp2f(f1 * w3.z);
        a0 = fmaf(w0.y, __builtin_amdgcn_rcpf(1.f + e00), a0);
        a0 = fmaf(w0.w, __builtin_amdgcn_rcpf(1.f + e01), a0);
        a1 = fmaf(w1.y, __builtin_amdgcn_rcpf(1.f + e10), a1);
        a1 = fmaf(w1.w, __builtin_amdgcn_rcpf(1.f + e11), a1);
        a2 = fmaf(w2.y, __builtin_amdgcn_rcpf(1.f + e20), a2);
        a2 = fmaf(w2.w, __builtin_amdgcn_rcpf(1.f + e21), a2);
        a3 = fmaf(w3.y, __builtin_amdgcn_rcpf(1.f + e30), a3);
        a3 = fmaf(w3.w, __builtin_amdgcn_rcpf(1.f + e31), a3);
    }
    if (valid) {
        size_t base = ((size_t)ch * NB + b) * NN;
        part[(base + n0 + 0) * 256 + s] = a0;
        part[(base + n0 + 1) * 256 + s] = a1;
        part[(base + n0 + 2) * 256 + s] = a2;
        part[(base + n0 + 3) * 256 + s] = a3;
    }
}

// ---------------------------------------------------------------------------
// K2b: sum 8 chunks, softmax over s, write split bf16 coef (SP-padded).
// grid (80 n, 8 b), block 256. part slots s in [196,256) are never written
// (finite poison); they only reach acc for t>=SB, which is masked below.
// ---------------------------------------------------------------------------
__global__ __launch_bounds__(256) void k2b(const float* __restrict__ part,
                                           __bf16* __restrict__ coefh,
                                           __bf16* __restrict__ coefl) {
    __shared__ float red[256];
    const int n = blockIdx.x;
    const int b = blockIdx.y;
    const int t = threadIdx.x;
    float acc = 0.f;
    #pragma unroll
    for (int ch = 0; ch < CH; ++ch)
        acc += part[(((size_t)ch * NB + b) * NN + n) * 256 + t];

    red[t] = (t < SB) ? acc : -1e30f;
    __syncthreads();
    #pragma unroll
    for (int off = 128; off > 0; off >>= 1) {
        if (t < off) red[t] = fmaxf(red[t], red[t + off]);
        __syncthreads();
    }
    float m = red[0];
    __syncthreads();
    float p = (t < SB) ? __expf(acc - m) : 0.f;
    red[t] = p;
    __syncthreads();
    #pragma unroll
    for (int off = 128; off > 0; off >>= 1) {
        if (t < off) red[t] += red[t + off];
        __syncthreads();
    }
    float inv = 1.f / red[0];
    if (t < SP) {
        float val = (t < SB) ? p * inv : 0.f;
        __bf16 h = (__bf16)val;
        __bf16 l = (__bf16)(val - (float)h);
        size_t base = ((size_t)b * NN + n) * SP + t;
        coefh[base] = h;
        coefl[base] = l;
    }
}

// ---------------------------------------------------------------------------
// K3 (MFMA, split precision): out[b][n][c] = sum_s coef[b][n][s] * X[b][c][s]
// out ~= Ah*Bh + Al*Bh + Ah*Bl. grid (32 c-tiles, 8 b), block 256.
// ---------------------------------------------------------------------------
__global__ __launch_bounds__(256) void k3_mfma(const __bf16* __restrict__ Xhi,
                                               const __bf16* __restrict__ Xlo,
                                               const __bf16* __restrict__ coefh,
                                               const __bf16* __restrict__ coefl,
                                               float* __restrict__ out) {
    const int t     = threadIdx.x;
    const int wave  = t >> 6;
    const int lane  = t & 63;
    const int quad  = lane >> 4;
    const int l16   = lane & 15;
    const int b     = blockIdx.y;
    const int cbase = blockIdx.x * 64 + wave * 16;

    const __bf16* Bh = Xhi + ((size_t)b * NC + cbase + l16) * SP + quad * 8;
    const __bf16* Bl = Xlo + ((size_t)b * NC + cbase + l16) * SP + quad * 8;
    const __bf16* Ah = coefh + ((size_t)b * NN + l16) * SP + quad * 8;
    const __bf16* Al = coefl + ((size_t)b * NN + l16) * SP + quad * 8;

    f32x4 acc[5] = {};

    #pragma unroll
    for (int k0 = 0; k0 < SP; k0 += 32) {
        v8bf bh = *(const v8bf*)(Bh + k0);
        v8bf bl = *(const v8bf*)(Bl + k0);
        #pragma unroll
        for (int mt = 0; mt < 5; ++mt) {
            v8bf ah = *(const v8bf*)(Ah + (size_t)mt * 16 * SP + k0);
            v8bf al = *(const v8bf*)(Al + (size_t)mt * 16 * SP + k0);
            acc[mt] = __builtin_amdgcn_mfma_f32_16x16x32_bf16(ah, bh, acc[mt], 0, 0, 0);
            acc[mt] = __builtin_amdgcn_mfma_f32_16x16x32_bf16(al, bh, acc[mt], 0, 0, 0);
            acc[mt] = __builtin_amdgcn_mfma_f32_16x16x32_bf16(ah, bl, acc[mt], 0, 0, 0);
        }
    }
    #pragma unroll
    for (int mt = 0; mt < 5; ++mt) {
        #pragma unroll
        for (int r = 0; r < 4; ++r) {
            int n = mt * 16 + quad * 4 + r;
            out[((size_t)b * NN + n) * NC + cbase + l16] = acc[mt][r];
        }
    }
}

// ---------------------------------------------------------------------------
// Workspace layout — NO aliasing (ws ~256 MB; peak use ~38 MB):
//   v(4K) | wpack(640K) | part(5.24M) | coefh(280K) | coefl(280K) |
//   W1b(4M) | Xt(6.42M) | F(6.42M) | Xhi(7.34M) | Xlo(7.34M)
// ---------------------------------------------------------------------------
extern "C" void kernel_launch(void* const* d_in, const int* in_sizes, int n_in,
                              void* d_out, int out_size, void* d_ws, size_t ws_size,
                              hipStream_t stream) {
    const float* X    = (const float*)d_in[0];  // [8][2048][196]
    const float* word = (const float*)d_in[1];  // [80][300]
    const float* W1   = (const float*)d_in[2];  // [1024][2048]
    const float* W2   = (const float*)d_in[3];  // [1024][300]
    const float* W3   = (const float*)d_in[4];  // [1024][1024]
    // d_in[5] = b3, d_in[7] = ba: cancel in softmax (uniform over s) -> unused
    const float* Wa   = (const float*)d_in[6];  // [1][1024]
    float* out = (float*)d_out;

    char* ws = (char*)d_ws;
    float*  v     = (float*)ws;                             // 1024 f
    float2* wpack = (float2*)(v + ND);                      // 80*1024 float2
    float*  part  = (float*)(wpack + (size_t)NN * ND);      // 8*8*80*256 f
    __bf16* coefh = (__bf16*)(part + (size_t)CH * NB * NN * 256);
    __bf16* coefl = coefh + (size_t)NB * NN * SP;
    __bf16* W1b   = coefl + (size_t)NB * NN * SP;           // 4.00 MB
    __bf16* Xt    = W1b + (size_t)ND * NC;                  // 6.42 MB
    float*  F     = (float*)(Xt + (size_t)NB * SB * NC);    // 6.42 MB
    __bf16* Xhi   = (__bf16*)(F + (size_t)NB * ND * SB);    // 7.34 MB
    __bf16* Xlo   = Xhi + (size_t)NB * NC * SP;             // 7.34 MB

    hipMemsetAsync(v, 0, ND * sizeof(float), stream);
    k0_v   <<<dim3(4, 16),         256, 0, stream>>>(W3, Wa, v);
    k0_fwd <<<dim3(NN, 4),         256, 0, stream>>>(word, W2, v, wpack);
    kcast_x<<<dim3(32, 4, 9),      256, 0, stream>>>(X, W1, Xt, Xhi, Xlo, W1b, F);
    k1_mfma<<<dim3(16, 4, NB * KS), 256, 0, stream>>>(Xt, W1b, F);
    k2a    <<<dim3(NN / 4, 7, CH), 256, 0, stream>>>(F, wpack, part);
    k2b    <<<dim3(NN, NB),        256, 0, stream>>>(part, coefh, coefl);
    k3_mfma<<<dim3(NC / 64, NB),   256, 0, stream>>>(Xhi, Xlo, coefh, coefl, out);
}

// Round 14
// 190.593 us; speedup vs baseline: 1.1366x; 1.0998x over previous
//
#include <hip/hip_runtime.h>
#include <math.h>

// Problem constants (match reference setup_inputs)
#define SB 196   // spatial s = h*w = 14*14
#define SP 224   // s padded to 7*32 for MFMA K-steps
#define NB 8     // batch
#define NBS (NB * SB)   // 1568 flattened (b,s)
#define NC 2048  // channels
#define ND 1024  // INTER_DIM
#define NN 80    // NUM_CLASSES
#define NW 300   // WORD_DIM
#define CH 8     // d-chunks in k2a
#define DCH (ND / CH)   // 128

typedef __bf16 v8bf __attribute__((ext_vector_type(8)));
typedef __bf16 v4bf __attribute__((ext_vector_type(4)));
typedef float  f32x4 __attribute__((ext_vector_type(4)));

// ---------------------------------------------------------------------------
// K0a: v[d] = sum_e Wa[e] * W3[e][d]   (Wa @ W3), accumulated via atomics.
// ---------------------------------------------------------------------------
__global__ __launch_bounds__(256) void k0_v(const float* __restrict__ W3,
                                            const float* __restrict__ Wa,
                                            float* __restrict__ v) {
    int d  = blockIdx.x * 256 + threadIdx.x;
    int e0 = blockIdx.y * 64;
    float p = 0.f;
    #pragma unroll 8
    for (int e = e0; e < e0 + 64; ++e) {
        p += Wa[e] * W3[(size_t)e * ND + d];   // coalesced over d
    }
    atomicAdd(&v[d], p);
}

// ---------------------------------------------------------------------------
// K0b: fwd[n][d] = sum_w word[n][w] * W2[d][w]; emits
//   wpack[n][d] = { 2*log2(e)*fwd, -2*v[d] }
// k2a computes logit' = sum_d wy / (1 + 2^(F*wx)) = ref logit - sum(v)
// (s-uniform constant, cancels in softmax over s). Runs after k0_v.
// ---------------------------------------------------------------------------
__global__ __launch_bounds__(256) void k0_fwd(const float* __restrict__ word,
                                              const float* __restrict__ W2,
                                              const float* __restrict__ v,
                                              float2* __restrict__ wpack) {
    __shared__ __align__(16) float lword[NW];
    int n = blockIdx.x;
    int d = blockIdx.y * 256 + threadIdx.x;
    for (int i = threadIdx.x; i < NW; i += 256) lword[i] = word[(size_t)n * NW + i];
    __syncthreads();
    const float4* wr = (const float4*)(W2 + (size_t)d * NW);
    const float4* l4 = (const float4*)lword;
    float acc = 0.f;
    #pragma unroll 5
    for (int i = 0; i < NW / 4; ++i) {
        float4 a = wr[i], b = l4[i];
        acc += a.x * b.x + a.y * b.y + a.z * b.z + a.w * b.w;
    }
    float2 o;
    o.x = 2.8853900817779268f * acc;   // 2*log2(e) * fwd[n][d]
    o.y = -2.f * v[d];
    wpack[(size_t)n * ND + d] = o;
}

// ---------------------------------------------------------------------------
// kcast_x: ONE pass over X [b][c][s] fp32 producing
//   Xt  [b][s][c]  bf16 (transposed, for k1 staging)
//   Xhi/Xlo [b][c][224] bf16 split (for k3), zero s-pad
// grid (32 c-tiles, 4 s-tiles, 9): z<8 = batch slice; z==8 = W1 fp32->bf16.
// ---------------------------------------------------------------------------
__global__ __launch_bounds__(256) void kcast_x(const float* __restrict__ X,
                                               const float* __restrict__ W1,
                                               __bf16* __restrict__ Xt,
                                               __bf16* __restrict__ Xhi,
                                               __bf16* __restrict__ Xlo,
                                               __bf16* __restrict__ W1b) {
    const int t = threadIdx.x;
    if (blockIdx.z == 8) {
        unsigned int slice_tid = (blockIdx.x * 4 + blockIdx.y) * 256 + t;
        #pragma unroll 4
        for (int r = 0; r < 16; ++r) {
            size_t i = ((size_t)slice_tid + (size_t)r * 32768) * 4;
            float4 f = *(const float4*)(W1 + i);
            v4bf o;
            o[0] = (__bf16)f.x; o[1] = (__bf16)f.y;
            o[2] = (__bf16)f.z; o[3] = (__bf16)f.w;
            *(v4bf*)(W1b + i) = o;
        }
        return;
    }
    __shared__ float tile[64][65];   // [c][s], +1 pad
    const int b  = blockIdx.z;
    const int c0 = blockIdx.x * 64;
    const int s0 = blockIdx.y * 64;
    const float* Xb = X + (size_t)b * NC * SB;
    {   // read: coalesced over s
        int ss = t & 63, cbase = t >> 6;
        #pragma unroll
        for (int r = 0; r < 16; ++r) {
            int cc = cbase + 4 * r;
            float val = (s0 + ss < SB) ? Xb[(size_t)(c0 + cc) * SB + s0 + ss] : 0.f;
            tile[cc][ss] = val;
        }
    }
    __syncthreads();
    {   // write 1: Xt transposed, coalesced over c
        int cc = t & 63, sbase = t >> 6;
        #pragma unroll
        for (int r = 0; r < 16; ++r) {
            int ss = sbase + 4 * r;
            if (s0 + ss < SB)
                Xt[((size_t)b * SB + s0 + ss) * NC + c0 + cc] = (__bf16)tile[cc][ss];
        }
    }
    {   // write 2: Xhi/Xlo direct orientation; zero the pad
        int ss = t & 63, cbase = t >> 6;
        int sg = s0 + ss;
        #pragma unroll
        for (int r = 0; r < 16; ++r) {
            int cc = cbase + 4 * r;
            if (sg < SP) {
                float val = (sg < SB) ? tile[cc][ss] : 0.f;
                __bf16 h = (__bf16)val;
                __bf16 l = (__bf16)(val - (float)h);
                size_t base = ((size_t)b * NC + c0 + cc) * SP + sg;
                Xhi[base] = h;
                Xlo[base] = l;
            }
        }
    }
}

// ---------------------------------------------------------------------------
// K1 (MFMA): F2[d][b*SB+s] = sum_c W1[d][c] * X[b][c][s], bf16 out (d-major
// layout, exactly what k2a's flattened (b,s) addressing wants; 3.2 MB ->
// L2-resident). EXACT R3-proven staging/K-loop/fragment layout; only the
// epilogue changed (bf16 cast + [d][1568] indexing).
// grid (16 d-tiles, 4 s-tiles, 8 b), block 256 (4 waves, 32x32 quadrants).
// (Banned variants: BK64+prefetch (R4/5 bug), no-LDS direct frags (R12,
// 5x worse), K-split+atomics (R13, atomic-bound).)
// ---------------------------------------------------------------------------
#define PITCH 40
__global__ __launch_bounds__(256) void k1_mfma(const __bf16* __restrict__ Xt,
                                               const __bf16* __restrict__ W1b,
                                               __bf16* __restrict__ F2) {
    __shared__ __align__(16) __bf16 lA[64 * PITCH];
    __shared__ __align__(16) __bf16 lB[64 * PITCH];
    const int t    = threadIdx.x;
    const int d0   = blockIdx.x * 64;
    const int s0   = blockIdx.y * 64;
    const int b    = blockIdx.z;
    const int lane = t & 63;
    const int wave = t >> 6;
    const int doff = (wave & 1) * 32;
    const int soff = (wave >> 1) * 32;
    const int quad = lane >> 4;
    const int l16  = lane & 15;

    f32x4 acc[2][2] = {};

    const int rr = t >> 2;
    const int cc = (t & 3) * 8;
    const bool sv = (s0 + rr) < SB;
    const __bf16* Ag = W1b + (size_t)(d0 + rr) * NC + cc;
    const __bf16* Bg = Xt + ((size_t)b * SB + (sv ? (s0 + rr) : 0)) * NC + cc;
    __bf16* lAw = lA + rr * PITCH + cc;
    __bf16* lBw = lB + rr * PITCH + cc;

    const __bf16* rA0 = lA + (doff + l16) * PITCH + quad * 8;
    const __bf16* rA1 = rA0 + 16 * PITCH;
    const __bf16* rB0 = lB + (soff + l16) * PITCH + quad * 8;
    const __bf16* rB1 = rB0 + 16 * PITCH;

    for (int k0 = 0; k0 < NC; k0 += 32) {
        uint4 a = *(const uint4*)(Ag + k0);
        uint4 bv = sv ? *(const uint4*)(Bg + k0) : make_uint4(0u, 0u, 0u, 0u);
        __syncthreads();
        *(uint4*)lAw = a;
        *(uint4*)lBw = bv;
        __syncthreads();
        v8bf a0 = *(const v8bf*)rA0;
        v8bf a1 = *(const v8bf*)rA1;
        v8bf b0 = *(const v8bf*)rB0;
        v8bf b1 = *(const v8bf*)rB1;
        acc[0][0] = __builtin_amdgcn_mfma_f32_16x16x32_bf16(a0, b0, acc[0][0], 0, 0, 0);
        acc[0][1] = __builtin_amdgcn_mfma_f32_16x16x32_bf16(a0, b1, acc[0][1], 0, 0, 0);
        acc[1][0] = __builtin_amdgcn_mfma_f32_16x16x32_bf16(a1, b0, acc[1][0], 0, 0, 0);
        acc[1][1] = __builtin_amdgcn_mfma_f32_16x16x32_bf16(a1, b1, acc[1][1], 0, 0, 0);
    }
    // epilogue: D[row = quad*4+r (d), col = l16 (s)] -> bf16 F2[d][b*SB+s]
    #pragma unroll
    for (int i = 0; i < 2; ++i) {
        #pragma unroll
        for (int j = 0; j < 2; ++j) {
            int s = s0 + soff + j * 16 + l16;
            if (s < SB) {
                #pragma unroll
                for (int r = 0; r < 4; ++r) {
                    int d = d0 + doff + i * 16 + quad * 4 + r;
                    F2[(size_t)d * NBS + b * SB + s] = (__bf16)acc[i][j][r];
                }
            }
        }
    }
}

// ---------------------------------------------------------------------------
// K2a v5: partial logits, 4-way n-tiling x 8 d-chunks, bf16 F in d-major
// layout -> every F load is a fully-coalesced 128B/wave L2-resident hit.
// part[ch][b][n][s] = sum_{d in chunk} wy/(1 + 2^(F*wx))
// grid (20 n-groups, 7 bs-tiles, 8 ch), block 256: idx = by*256+t over (b,s).
// ---------------------------------------------------------------------------
__global__ __launch_bounds__(256) void k2a(const __bf16* __restrict__ F2,
                                           const float2* __restrict__ wpack,
                                           float* __restrict__ part) {
    const int n0  = blockIdx.x * 4;
    const int ch  = blockIdx.z;
    const int idx = blockIdx.y * 256 + threadIdx.x;   // (b,s) flat, valid <1568
    const bool valid = idx < NBS;
    const int iv = valid ? idx : 0;
    const int b  = iv / SB;          // magic-mul div by 196
    const int s  = iv - b * SB;
    const __bf16* Fp = F2 + (size_t)(ch * DCH) * NBS + iv;
    const float4* wp0 = (const float4*)(wpack + (size_t)(n0 + 0) * ND + ch * DCH);
    const float4* wp1 = (const float4*)(wpack + (size_t)(n0 + 1) * ND + ch * DCH);
    const float4* wp2 = (const float4*)(wpack + (size_t)(n0 + 2) * ND + ch * DCH);
    const float4* wp3 = (const float4*)(wpack + (size_t)(n0 + 3) * ND + ch * DCH);
    float a0 = 0.f, a1 = 0.f, a2 = 0.f, a3 = 0.f;
    #pragma unroll 4
    for (int d2 = 0; d2 < DCH / 2; ++d2) {
        float f0 = (float)Fp[(size_t)(2 * d2)     * NBS];
        float f1 = (float)Fp[(size_t)(2 * d2 + 1) * NBS];
        float4 w0 = wp0[d2];   // {wx0, wy0, wx1, wy1} wave-uniform s_load
        float4 w1 = wp1[d2];
        float4 w2 = wp2[d2];
        float4 w3 = wp3[d2];
        float e00 = __builtin_amdgcn_exp2f(f0 * w0.x);
        float e01 = __builtin_amdgcn_exp2f(f1 * w0.z);
        float e10 = __builtin_amdgcn_exp2f(f0 * w1.x);
        float e11 = __builtin_amdgcn_exp2f(f1 * w1.z);
        float e20 = __builtin_amdgcn_exp2f(f0 * w2.x);
        float e21 = __builtin_amdgcn_exp2f(f1 * w2.z);
        float e30 = __builtin_amdgcn_exp2f(f0 * w3.x);
        float e31 = __builtin_amdgcn_exp2f(f1 * w3.z);
        a0 = fmaf(w0.y, __builtin_amdgcn_rcpf(1.f + e00), a0);
        a0 = fmaf(w0.w, __builtin_amdgcn_rcpf(1.f + e01), a0);
        a1 = fmaf(w1.y, __builtin_amdgcn_rcpf(1.f + e10), a1);
        a1 = fmaf(w1.w, __builtin_amdgcn_rcpf(1.f + e11), a1);
        a2 = fmaf(w2.y, __builtin_amdgcn_rcpf(1.f + e20), a2);
        a2 = fmaf(w2.w, __builtin_amdgcn_rcpf(1.f + e21), a2);
        a3 = fmaf(w3.y, __builtin_amdgcn_rcpf(1.f + e30), a3);
        a3 = fmaf(w3.w, __builtin_amdgcn_rcpf(1.f + e31), a3);
    }
    if (valid) {
        size_t base = ((size_t)ch * NB + b) * NN;
        part[(base + n0 + 0) * 256 + s] = a0;
        part[(base + n0 + 1) * 256 + s] = a1;
        part[(base + n0 + 2) * 256 + s] = a2;
        part[(base + n0 + 3) * 256 + s] = a3;
    }
}

// ---------------------------------------------------------------------------
// K2b: sum 8 chunks, softmax over s, write split bf16 coef (SP-padded).
// grid (80 n, 8 b), block 256. part slots s in [196,256) are never written
// (finite poison); they only reach acc for t>=SB, which is masked below.
// ---------------------------------------------------------------------------
__global__ __launch_bounds__(256) void k2b(const float* __restrict__ part,
                                           __bf16* __restrict__ coefh,
                                           __bf16* __restrict__ coefl) {
    __shared__ float red[256];
    const int n = blockIdx.x;
    const int b = blockIdx.y;
    const int t = threadIdx.x;
    float acc = 0.f;
    #pragma unroll
    for (int ch = 0; ch < CH; ++ch)
        acc += part[(((size_t)ch * NB + b) * NN + n) * 256 + t];

    red[t] = (t < SB) ? acc : -1e30f;
    __syncthreads();
    #pragma unroll
    for (int off = 128; off > 0; off >>= 1) {
        if (t < off) red[t] = fmaxf(red[t], red[t + off]);
        __syncthreads();
    }
    float m = red[0];
    __syncthreads();
    float p = (t < SB) ? __expf(acc - m) : 0.f;
    red[t] = p;
    __syncthreads();
    #pragma unroll
    for (int off = 128; off > 0; off >>= 1) {
        if (t < off) red[t] += red[t + off];
        __syncthreads();
    }
    float inv = 1.f / red[0];
    if (t < SP) {
        float val = (t < SB) ? p * inv : 0.f;
        __bf16 h = (__bf16)val;
        __bf16 l = (__bf16)(val - (float)h);
        size_t base = ((size_t)b * NN + n) * SP + t;
        coefh[base] = h;
        coefl[base] = l;
    }
}

// ---------------------------------------------------------------------------
// K3 (MFMA, split precision): out[b][n][c] = sum_s coef[b][n][s] * X[b][c][s]
// out ~= Ah*Bh + Al*Bh + Ah*Bl. grid (32 c-tiles, 8 b), block 256.
// ---------------------------------------------------------------------------
__global__ __launch_bounds__(256) void k3_mfma(const __bf16* __restrict__ Xhi,
                                               const __bf16* __restrict__ Xlo,
                                               const __bf16* __restrict__ coefh,
                                               const __bf16* __restrict__ coefl,
                                               float* __restrict__ out) {
    const int t     = threadIdx.x;
    const int wave  = t >> 6;
    const int lane  = t & 63;
    const int quad  = lane >> 4;
    const int l16   = lane & 15;
    const int b     = blockIdx.y;
    const int cbase = blockIdx.x * 64 + wave * 16;

    const __bf16* Bh = Xhi + ((size_t)b * NC + cbase + l16) * SP + quad * 8;
    const __bf16* Bl = Xlo + ((size_t)b * NC + cbase + l16) * SP + quad * 8;
    const __bf16* Ah = coefh + ((size_t)b * NN + l16) * SP + quad * 8;
    const __bf16* Al = coefl + ((size_t)b * NN + l16) * SP + quad * 8;

    f32x4 acc[5] = {};

    #pragma unroll
    for (int k0 = 0; k0 < SP; k0 += 32) {
        v8bf bh = *(const v8bf*)(Bh + k0);
        v8bf bl = *(const v8bf*)(Bl + k0);
        #pragma unroll
        for (int mt = 0; mt < 5; ++mt) {
            v8bf ah = *(const v8bf*)(Ah + (size_t)mt * 16 * SP + k0);
            v8bf al = *(const v8bf*)(Al + (size_t)mt * 16 * SP + k0);
            acc[mt] = __builtin_amdgcn_mfma_f32_16x16x32_bf16(ah, bh, acc[mt], 0, 0, 0);
            acc[mt] = __builtin_amdgcn_mfma_f32_16x16x32_bf16(al, bh, acc[mt], 0, 0, 0);
            acc[mt] = __builtin_amdgcn_mfma_f32_16x16x32_bf16(ah, bl, acc[mt], 0, 0, 0);
        }
    }
    #pragma unroll
    for (int mt = 0; mt < 5; ++mt) {
        #pragma unroll
        for (int r = 0; r < 4; ++r) {
            int n = mt * 16 + quad * 4 + r;
            out[((size_t)b * NN + n) * NC + cbase + l16] = acc[mt][r];
        }
    }
}

// ---------------------------------------------------------------------------
// Workspace layout — NO aliasing (ws ~256 MB; peak use ~35 MB):
//   v(4K) | wpack(640K) | part(5.24M) | coefh(280K) | coefl(280K) |
//   W1b(4M) | Xt(6.42M) | F2(3.21M bf16) | Xhi(7.34M) | Xlo(7.34M)
// ---------------------------------------------------------------------------
extern "C" void kernel_launch(void* const* d_in, const int* in_sizes, int n_in,
                              void* d_out, int out_size, void* d_ws, size_t ws_size,
                              hipStream_t stream) {
    const float* X    = (const float*)d_in[0];  // [8][2048][196]
    const float* word = (const float*)d_in[1];  // [80][300]
    const float* W1   = (const float*)d_in[2];  // [1024][2048]
    const float* W2   = (const float*)d_in[3];  // [1024][300]
    const float* W3   = (const float*)d_in[4];  // [1024][1024]
    // d_in[5] = b3, d_in[7] = ba: cancel in softmax (uniform over s) -> unused
    const float* Wa   = (const float*)d_in[6];  // [1][1024]
    float* out = (float*)d_out;

    char* ws = (char*)d_ws;
    float*  v     = (float*)ws;                             // 1024 f
    float2* wpack = (float2*)(v + ND);                      // 80*1024 float2
    float*  part  = (float*)(wpack + (size_t)NN * ND);      // 8*8*80*256 f
    __bf16* coefh = (__bf16*)(part + (size_t)CH * NB * NN * 256);
    __bf16* coefl = coefh + (size_t)NB * NN * SP;
    __bf16* W1b   = coefl + (size_t)NB * NN * SP;           // 4.00 MB
    __bf16* Xt    = W1b + (size_t)ND * NC;                  // 6.42 MB
    __bf16* F2    = Xt + (size_t)NB * SB * NC;              // 3.21 MB (bf16)
    __bf16* Xhi   = F2 + (size_t)ND * NBS;                  // 7.34 MB
    __bf16* Xlo   = Xhi + (size_t)NB * NC * SP;             // 7.34 MB

    hipMemsetAsync(v, 0, ND * sizeof(float), stream);
    k0_v   <<<dim3(4, 16),         256, 0, stream>>>(W3, Wa, v);
    k0_fwd <<<dim3(NN, 4),         256, 0, stream>>>(word, W2, v, wpack);
    kcast_x<<<dim3(32, 4, 9),      256, 0, stream>>>(X, W1, Xt, Xhi, Xlo, W1b);
    k1_mfma<<<dim3(16, 4, NB),     256, 0, stream>>>(Xt, W1b, F2);
    k2a    <<<dim3(NN / 4, 7, CH), 256, 0, stream>>>(F2, wpack, part);
    k2b    <<<dim3(NN, NB),        256, 0, stream>>>(part, coefh, coefl);
    k3_mfma<<<dim3(NC / 64, NB),   256, 0, stream>>>(Xhi, Xlo, coefh, coefl, out);
}